// Round 6
// baseline (198.080 us; speedup 1.0000x reference)
//
#include <hip/hip_runtime.h>

// 24-qubit brickwork circuit. 3 passes, register-resident gates.
// State: flat index i in [0, 2^24), wire w <-> bit (23-w).
// Gate on wires (w,w+1): p1 = 22-w, p0 = 23-w. M[v][u] = G[u0,v0,u1,v1],
// u = (u0<<1)|u1, u0 = bit p0, u1 = bit p1 (v likewise).
//
// pass1: 256 thr, 14-bit tile {0..13}, init fused, 24 gates (wires 10..23).
// pass2a: 128 thr, 13-bit tile {0..5}u{11..17}, 8 gates, 1 transpose.
// pass2b: 128 thr, 13-bit tile {0..3}u{15..23}, 14 gates, 2 transposes.
// All LDS transposes swizzled to <=2 lanes/bank (free per m136).

#define SWZ(j) ((j) ^ (((j) >> 6) & 15) ^ ((((j) >> 10) & 1) << 4))
#define SWZ13(j) ((j) ^ (((j) >> 5) & 31) ^ ((((j) >> 9) & 1) << 1) ^ ((((j) >> 10) & 1) << 4))
#define DEL(x, S) (((x) & ((1 << (S)) - 1)) | (((x) >> ((S) + 1)) << (S)))

// Gate acting on reg bits B0 (holds p1 / u1) and B1 (holds p0 / u0).
template<int B0, int B1>
__device__ __forceinline__ void gate_sc(float v[64], const float* __restrict__ g) {
  float m[16];
#pragma unroll
  for (int vv = 0; vv < 4; ++vv)
#pragma unroll
    for (int uu = 0; uu < 4; ++uu)
      m[vv * 4 + uu] = g[(uu >> 1) * 8 + (vv >> 1) * 4 + (uu & 1) * 2 + (vv & 1)];
  constexpr int S1 = 1 << B0;  // u1 stride
  constexpr int S0 = 1 << B1;  // u0 stride
#pragma unroll
  for (int b = 0; b < 64; ++b) {
    if (b & (S0 | S1)) continue;
    const float a0 = v[b], a1 = v[b + S1], a2 = v[b + S0], a3 = v[b + S0 + S1];
    v[b]           = m[0]  * a0 + m[1]  * a1 + m[2]  * a2 + m[3]  * a3;
    v[b + S1]      = m[4]  * a0 + m[5]  * a1 + m[6]  * a2 + m[7]  * a3;
    v[b + S0]      = m[8]  * a0 + m[9]  * a1 + m[10] * a2 + m[11] * a3;
    v[b + S0 + S1] = m[12] * a0 + m[13] * a1 + m[14] * a2 + m[15] * a3;
  }
}

// ---------- pass1 layouts (14-bit j, t = 8 bits) ----------
#define JB1(t, r) ((t) | ((r) << 8))
#define JM1(t, r) (((t) & 15) | ((((r) >> 1) & 15) << 4) | (((r) & 1) << 8) | (((r) >> 5) << 9) | (((t) >> 4) << 10))
#define JA1(t, r) (((r) & 3) | ((((r) >> 3) & 7) << 2) | ((((r) >> 2) & 1) << 5) | ((t) << 6))
#define JW1(t, r) (((t) & 31) | ((((r) >> 2) & 1) << 5) | (((r) & 1) << 6) | ((((r) >> 1) & 1) << 7) | ((((r) >> 3) & 7) << 8) | (((t) >> 5) << 11))

// ---------- pass2 layouts (13-bit j, t = 7 bits) ----------
// F (load): r = {j0,j1,j9,j10,j11,j12}, t = j2..8
#define JF2(t, r) (((r) & 3) | (((t) & 127) << 2) | (((r) >> 2) << 9))
// pass2a P*: r = (j6,j7,j9,j8,j10,j11), t = {j0..j5, j12}
#define JPA(t, r) (((t) & 63) | (((r) & 1) << 6) | ((((r) >> 1) & 1) << 7) | ((((r) >> 3) & 1) << 8) | ((((r) >> 2) & 1) << 9) | ((((r) >> 4) & 3) << 10) | (((t) >> 6) << 12))
// pass2b P1: r = j7..j12, t = j0..6
#define JP1(t, r) (((t) & 127) | ((r) << 7))
// pass2b P2: r = (j7,j4,j5,j6,j8,j9), t = {j0..j3, j10..j12}
#define JP2(t, r) (((t) & 15) | ((((r) >> 1) & 7) << 4) | (((r) & 1) << 7) | ((((r) >> 4) & 3) << 8) | (((t) >> 4) << 10))

// 2-stage in-place transpose (14-bit, buf 8192, pass1)
#define TRANS(JW, JR, S, RBIT)                                        \
  do {                                                                \
    _Pragma("unroll")                                                 \
    for (int r = 0; r < 64; ++r) if ((((r) >> (RBIT)) & 1) == 0)      \
      buf[DEL(SWZ(JW(t, r)), S)] = v[r];                              \
    __syncthreads();                                                  \
    _Pragma("unroll")                                                 \
    for (int r = 0; r < 64; ++r) if ((((r) >> (RBIT)) & 1) == 0)      \
      v[r] = buf[DEL(SWZ(JR(t, r)), S)];                              \
    __syncthreads();                                                  \
    _Pragma("unroll")                                                 \
    for (int r = 0; r < 64; ++r) if ((((r) >> (RBIT)) & 1) == 1)      \
      buf[DEL(SWZ(JW(t, r)), S)] = v[r];                              \
    __syncthreads();                                                  \
    _Pragma("unroll")                                                 \
    for (int r = 0; r < 64; ++r) if ((((r) >> (RBIT)) & 1) == 1)      \
      v[r] = buf[DEL(SWZ(JR(t, r)), S)];                              \
    __syncthreads();                                                  \
  } while (0)

// 2-stage in-place transpose (13-bit, buf 4096, pass2)
#define TRANS13(JW, JR, S, RBIT)                                      \
  do {                                                                \
    _Pragma("unroll")                                                 \
    for (int r = 0; r < 64; ++r) if ((((r) >> (RBIT)) & 1) == 0)      \
      buf[DEL(SWZ13(JW(t, r)), S)] = v[r];                            \
    __syncthreads();                                                  \
    _Pragma("unroll")                                                 \
    for (int r = 0; r < 64; ++r) if ((((r) >> (RBIT)) & 1) == 0)      \
      v[r] = buf[DEL(SWZ13(JR(t, r)), S)];                            \
    __syncthreads();                                                  \
    _Pragma("unroll")                                                 \
    for (int r = 0; r < 64; ++r) if ((((r) >> (RBIT)) & 1) == 1)      \
      buf[DEL(SWZ13(JW(t, r)), S)] = v[r];                            \
    __syncthreads();                                                  \
    _Pragma("unroll")                                                 \
    for (int r = 0; r < 64; ++r) if ((((r) >> (RBIT)) & 1) == 1)      \
      v[r] = buf[DEL(SWZ13(JR(t, r)), S)];                            \
    __syncthreads();                                                  \
  } while (0)

// ---------------- Pass 1: init + 24 gates on bits 0..13 (wires 10..23) -------
__global__ __launch_bounds__(256) void k_pass1(
    const float* __restrict__ states, const float* __restrict__ gates,
    float* __restrict__ out) {
  __shared__ float buf[8192];
  const int t = threadIdx.x;
  const int b = blockIdx.x;  // global bits 14..23 (wires 9..0)

  {
    float p = 1.f;
    for (int k = 0; k < 8; ++k) p *= states[(23 - k) * 2 + ((t >> k) & 1)];
    buf[t] = p;  // sLo over j0..7 (wires 23..16)
    if (t < 64) {
      float q = 1.f;
      for (int k = 0; k < 6; ++k) q *= states[(15 - k) * 2 + ((t >> k) & 1)];
      buf[256 + t] = q;  // sHi over j8..13 (wires 15..10)
    }
  }
  float pref = 1.f;
  for (int k = 0; k < 10; ++k) pref *= states[(9 - k) * 2 + ((b >> k) & 1)];
  __syncthreads();

  float v[64];
  const float plT = pref * buf[t];
#pragma unroll
  for (int r = 0; r < 64; ++r) v[r] = plT * buf[256 + r];  // B layout: r=j8..13
  __syncthreads();

  // Phase B (r=[j8..13])
  gate_sc<4, 5>(v, gates + 16 * 5);
  gate_sc<2, 3>(v, gates + 16 * 6);
  gate_sc<0, 1>(v, gates + 16 * 7);
  gate_sc<3, 4>(v, gates + 16 * 17);
  gate_sc<1, 2>(v, gates + 16 * 18);
  gate_sc<2, 3>(v, gates + 16 * 29);
  TRANS(JB1, JM1, 8, 0);
  // Phase M (r=[j8,j4,j5,j6,j7,j9])
  gate_sc<3, 4>(v, gates + 16 * 8);
  gate_sc<1, 2>(v, gates + 16 * 9);
  gate_sc<4, 0>(v, gates + 16 * 19);
  gate_sc<2, 3>(v, gates + 16 * 20);
  gate_sc<0, 5>(v, gates + 16 * 30);
  gate_sc<3, 4>(v, gates + 16 * 31);
  TRANS(JM1, JA1, 5, 2);
  // Phase A (r=[j0,j1,j5,j2,j3,j4])
  gate_sc<3, 4>(v, gates + 16 * 10);
  gate_sc<0, 1>(v, gates + 16 * 11);
  gate_sc<4, 5>(v, gates + 16 * 21);
  gate_sc<1, 3>(v, gates + 16 * 22);
  gate_sc<5, 2>(v, gates + 16 * 32);
  gate_sc<3, 4>(v, gates + 16 * 33);
  gate_sc<0, 1>(v, gates + 16 * 34);
  gate_sc<4, 5>(v, gates + 16 * 44);
  gate_sc<1, 3>(v, gates + 16 * 45);
  TRANS(JA1, JW1, 5, 2);
  // Phase W (r=[j6,j7,j5,j8,j9,j10])
  gate_sc<4, 5>(v, gates + 16 * 41);
  gate_sc<1, 3>(v, gates + 16 * 42);
  gate_sc<2, 0>(v, gates + 16 * 43);

  const long long ob = ((long long)b) << 14;
#pragma unroll
  for (int r = 0; r < 64; ++r) out[ob | JW1(t, r)] = v[r];
}

// ---------------- Pass 2a: 8 gates, tile = {0..5} u {11..17}, 128 thr --------
// local j0..5 = global 0..5; j6..12 = global 11..17. block: {6..10} u {18..23}
// gates (local bits): g3(11,12) g4(9,10) g15(10,11) | g16(8,9) g27(9,10)
//                     g28(7,8) g39(8,9) g40(6,7)
__global__ __launch_bounds__(128) void k_pass2a(
    const float* __restrict__ gates, float* __restrict__ out) {
  __shared__ float buf[4096];
  const int t = threadIdx.x;
  const int b = blockIdx.x;
  const long long base0 = ((long long)(b & 31) << 6) | ((long long)(b >> 5) << 18);

  float v[64];
  // load in F layout: float4, 256B runs
#pragma unroll
  for (int c = 0; c < 16; ++c) {
    float4 x = *(const float4*)(&out[base0 + ((t & 15) << 2) + ((long long)((t >> 4) | (c << 3)) << 11)]);
    v[4 * c] = x.x; v[4 * c + 1] = x.y; v[4 * c + 2] = x.z; v[4 * c + 3] = x.w;
  }
  // Phase F (r={j0,j1,j9,j10,j11,j12}): g3(11,12) g4(9,10) g15(10,11)
  gate_sc<4, 5>(v, gates + 16 * 3);
  gate_sc<2, 3>(v, gates + 16 * 4);
  gate_sc<3, 4>(v, gates + 16 * 15);
  TRANS13(JF2, JPA, 9, 2);  // split j9 @ r2 in both layouts
  // Phase P* (r=(j6,j7,j9,j8,j10,j11)): g16(8,9) g27(9,10) g28(7,8) g39(8,9) g40(6,7)
  gate_sc<3, 2>(v, gates + 16 * 16);
  gate_sc<2, 4>(v, gates + 16 * 27);
  gate_sc<1, 3>(v, gates + 16 * 28);
  gate_sc<3, 2>(v, gates + 16 * 39);
  gate_sc<0, 1>(v, gates + 16 * 40);

  // store from P*: scalar, 256B runs (lanes = j0..5)
#pragma unroll
  for (int r = 0; r < 64; ++r) {
    const int j = JPA(t, r);
    out[base0 | (j & 63) | ((long long)(j >> 6) << 11)] = v[r];
  }
}

// ---------------- Pass 2b: 14 gates, tile = {0..3} u {15..23}, 128 thr -------
// local j0..3 = global 0..3; j4..12 = global 15..23. block: global 4..14
// gates (local bits): g0(11,12) g1(9,10) g12(10,11) g23(11,12) | g2(7,8)
//   g13(8,9) g24(9,10) g35(10,11) | g14(6,7) g25(7,8) g26(5,6) g36(8,9)
//   g37(6,7) g38(4,5)
__global__ __launch_bounds__(128) void k_pass2b(
    const float* __restrict__ gates, float* __restrict__ out) {
  __shared__ float buf[4096];
  const int t = threadIdx.x;
  const int b = blockIdx.x;

  float v[64];
  // load in F layout: float4, 64B runs
#pragma unroll
  for (int c = 0; c < 16; ++c) {
    float4 x = *(const float4*)(&out[((t & 3) << 2) + ((long long)b << 4) + ((long long)((t >> 2) | (c << 5)) << 15)]);
    v[4 * c] = x.x; v[4 * c + 1] = x.y; v[4 * c + 2] = x.z; v[4 * c + 3] = x.w;
  }
  // Phase F (r={j0,j1,j9,j10,j11,j12}): g0(11,12) g1(9,10) g12(10,11) g23(11,12)
  gate_sc<4, 5>(v, gates + 16 * 0);
  gate_sc<2, 3>(v, gates + 16 * 1);
  gate_sc<3, 4>(v, gates + 16 * 12);
  gate_sc<4, 5>(v, gates + 16 * 23);
  TRANS13(JF2, JP1, 10, 3);  // split j10 @ r3
  // Phase P1 (r=j7..j12): g2(7,8) g13(8,9) g24(9,10) g35(10,11)
  gate_sc<0, 1>(v, gates + 16 * 2);
  gate_sc<1, 2>(v, gates + 16 * 13);
  gate_sc<2, 3>(v, gates + 16 * 24);
  gate_sc<3, 4>(v, gates + 16 * 35);
  TRANS13(JP1, JP2, 7, 0);  // split j7 @ r0
  // Phase P2 (r=(j7,j4,j5,j6,j8,j9)): g14(6,7) g25(7,8) g26(5,6) g36(8,9)
  //                                    g37(6,7) g38(4,5)
  gate_sc<3, 0>(v, gates + 16 * 14);
  gate_sc<0, 4>(v, gates + 16 * 25);
  gate_sc<2, 3>(v, gates + 16 * 26);
  gate_sc<4, 5>(v, gates + 16 * 36);
  gate_sc<3, 0>(v, gates + 16 * 37);
  gate_sc<1, 2>(v, gates + 16 * 38);

  // store from P2: scalar, 64B runs (lanes = j0..3)
#pragma unroll
  for (int r = 0; r < 64; ++r) {
    const int j = JP2(t, r);
    out[(j & 15) | ((long long)b << 4) | ((long long)(j >> 4) << 15)] = v[r];
  }
}

extern "C" void kernel_launch(void* const* d_in, const int* in_sizes, int n_in,
                              void* d_out, int out_size, void* d_ws, size_t ws_size,
                              hipStream_t stream) {
  const float* states = (const float*)d_in[0];  // (24, 2) f32
  const float* gates = (const float*)d_in[1];   // (46, 2,2,2,2) f32
  float* out = (float*)d_out;                   // 2^24 f32

  k_pass1<<<1024, 256, 0, stream>>>(states, gates, out);
  k_pass2a<<<2048, 128, 0, stream>>>(gates, out);
  k_pass2b<<<2048, 128, 0, stream>>>(gates, out);
}

// Round 7
// 183.753 us; speedup vs baseline: 1.0780x; 1.0780x over previous
//
#include <hip/hip_runtime.h>

// 24-qubit brickwork circuit. 3 passes, register-resident gates.
// State: flat index i in [0, 2^24), wire w <-> bit (23-w).
// Gate on wires (w,w+1): p1 = 22-w (low bit), p0 = p1+1. M[v][u] = G[u0,v0,u1,v1].
//
// pass1: 256 thr, tile bits {0..13}, init fused, 24 gates (wires 10..23).
// pass2a: 256 thr, tile {0..6}u{11..17}, 8 gates (wires 6..12), 1x 4-stage
//         transpose, float4 loads (512B runs), float2 stores (512B runs).
// pass2b: 256 thr, tile {0..4}u{15..23}, 14 gates (wires 0..8), 2x 4-stage
//         transposes, float4 loads / scalar stores (128B runs).
// All LDS transpose patterns verified <=2 lanes/bank (free per m136).

#define SWZ(j) ((j) ^ (((j) >> 6) & 15) ^ ((((j) >> 10) & 1) << 4))
#define DEL(x, S) (((x) & ((1 << (S)) - 1)) | (((x) >> ((S) + 1)) << (S)))

// Gate acting on reg bits B0 (holds p1 / u1) and B1 (holds p0 / u0).
template<int B0, int B1>
__device__ __forceinline__ void gate_sc(float v[64], const float* __restrict__ g) {
  float m[16];
#pragma unroll
  for (int vv = 0; vv < 4; ++vv)
#pragma unroll
    for (int uu = 0; uu < 4; ++uu)
      m[vv * 4 + uu] = g[(uu >> 1) * 8 + (vv >> 1) * 4 + (uu & 1) * 2 + (vv & 1)];
  constexpr int S1 = 1 << B0;  // u1 stride
  constexpr int S0 = 1 << B1;  // u0 stride
#pragma unroll
  for (int b = 0; b < 64; ++b) {
    if (b & (S0 | S1)) continue;
    const float a0 = v[b], a1 = v[b + S1], a2 = v[b + S0], a3 = v[b + S0 + S1];
    v[b]           = m[0]  * a0 + m[1]  * a1 + m[2]  * a2 + m[3]  * a3;
    v[b + S1]      = m[4]  * a0 + m[5]  * a1 + m[6]  * a2 + m[7]  * a3;
    v[b + S0]      = m[8]  * a0 + m[9]  * a1 + m[10] * a2 + m[11] * a3;
    v[b + S0 + S1] = m[12] * a0 + m[13] * a1 + m[14] * a2 + m[15] * a3;
  }
}

// ---------- pass1 layouts (14-bit j, t = 8 bits) ----------
#define JB1(t, r) ((t) | ((r) << 8))
#define JM1(t, r) (((t) & 15) | ((((r) >> 1) & 15) << 4) | (((r) & 1) << 8) | (((r) >> 5) << 9) | (((t) >> 4) << 10))
#define JA1(t, r) (((r) & 3) | ((((r) >> 3) & 7) << 2) | ((((r) >> 2) & 1) << 5) | ((t) << 6))
#define JW1(t, r) (((t) & 31) | ((((r) >> 2) & 1) << 5) | (((r) & 1) << 6) | ((((r) >> 1) & 1) << 7) | ((((r) >> 3) & 7) << 8) | (((t) >> 5) << 11))

// 2-stage in-place transpose (pass1, buf 8192 floats)
#define TRANS(JW, JR, S, RBIT)                                        \
  do {                                                                \
    _Pragma("unroll")                                                 \
    for (int r = 0; r < 64; ++r) if ((((r) >> (RBIT)) & 1) == 0)      \
      buf[DEL(SWZ(JW(t, r)), S)] = v[r];                              \
    __syncthreads();                                                  \
    _Pragma("unroll")                                                 \
    for (int r = 0; r < 64; ++r) if ((((r) >> (RBIT)) & 1) == 0)      \
      v[r] = buf[DEL(SWZ(JR(t, r)), S)];                              \
    __syncthreads();                                                  \
    _Pragma("unroll")                                                 \
    for (int r = 0; r < 64; ++r) if ((((r) >> (RBIT)) & 1) == 1)      \
      buf[DEL(SWZ(JW(t, r)), S)] = v[r];                              \
    __syncthreads();                                                  \
    _Pragma("unroll")                                                 \
    for (int r = 0; r < 64; ++r) if ((((r) >> (RBIT)) & 1) == 1)      \
      v[r] = buf[DEL(SWZ(JR(t, r)), S)];                              \
    __syncthreads();                                                  \
  } while (0)

// 4-stage in-place transpose (pass2, buf 4096 floats). Split bits at reg
// positions RA, RB (same in both layouts); BIDX maps j -> 12-bit buf index.
#define T4STAGE(JW, JR, RA, RB, SA, SB, BIDX)                         \
    _Pragma("unroll")                                                 \
    for (int r = 0; r < 64; ++r)                                      \
      if (((((r) >> (RA)) & 1) == (SA)) && ((((r) >> (RB)) & 1) == (SB))) \
        buf[BIDX(JW(t, r))] = v[r];                                   \
    __syncthreads();                                                  \
    _Pragma("unroll")                                                 \
    for (int r = 0; r < 64; ++r)                                      \
      if (((((r) >> (RA)) & 1) == (SA)) && ((((r) >> (RB)) & 1) == (SB))) \
        v[r] = buf[BIDX(JR(t, r))];                                   \
    __syncthreads();

#define TRANS4(JW, JR, RA, RB, BIDX)                                  \
  do {                                                                \
    T4STAGE(JW, JR, RA, RB, 0, 0, BIDX)                               \
    T4STAGE(JW, JR, RA, RB, 0, 1, BIDX)                               \
    T4STAGE(JW, JR, RA, RB, 1, 0, BIDX)                               \
    T4STAGE(JW, JR, RA, RB, 1, 1, BIDX)                               \
  } while (0)

#define BSWZ(x) ((x) ^ (((x) >> 5) & 31))

// ---------------- Pass 1: init + 24 gates on bits 0..13 (wires 10..23) -------
__global__ __launch_bounds__(256) void k_pass1(
    const float* __restrict__ states, const float* __restrict__ gates,
    float* __restrict__ out) {
  __shared__ float buf[8192];
  const int t = threadIdx.x;
  const int b = blockIdx.x;  // global bits 14..23 (wires 9..0)

  {
    float p = 1.f;
    for (int k = 0; k < 8; ++k) p *= states[(23 - k) * 2 + ((t >> k) & 1)];
    buf[t] = p;  // sLo over j0..7 (wires 23..16)
    if (t < 64) {
      float q = 1.f;
      for (int k = 0; k < 6; ++k) q *= states[(15 - k) * 2 + ((t >> k) & 1)];
      buf[256 + t] = q;  // sHi over j8..13 (wires 15..10)
    }
  }
  float pref = 1.f;
  for (int k = 0; k < 10; ++k) pref *= states[(9 - k) * 2 + ((b >> k) & 1)];
  __syncthreads();

  float v[64];
  const float plT = pref * buf[t];
#pragma unroll
  for (int r = 0; r < 64; ++r) v[r] = plT * buf[256 + r];  // B layout: r=j8..13
  __syncthreads();

  // Phase B (r=[j8..13])
  gate_sc<4, 5>(v, gates + 16 * 5);
  gate_sc<2, 3>(v, gates + 16 * 6);
  gate_sc<0, 1>(v, gates + 16 * 7);
  gate_sc<3, 4>(v, gates + 16 * 17);
  gate_sc<1, 2>(v, gates + 16 * 18);
  gate_sc<2, 3>(v, gates + 16 * 29);
  TRANS(JB1, JM1, 8, 0);
  // Phase M (r=[j8,j4,j5,j6,j7,j9])
  gate_sc<3, 4>(v, gates + 16 * 8);
  gate_sc<1, 2>(v, gates + 16 * 9);
  gate_sc<4, 0>(v, gates + 16 * 19);
  gate_sc<2, 3>(v, gates + 16 * 20);
  gate_sc<0, 5>(v, gates + 16 * 30);
  gate_sc<3, 4>(v, gates + 16 * 31);
  TRANS(JM1, JA1, 5, 2);
  // Phase A (r=[j0,j1,j5,j2,j3,j4])
  gate_sc<3, 4>(v, gates + 16 * 10);
  gate_sc<0, 1>(v, gates + 16 * 11);
  gate_sc<4, 5>(v, gates + 16 * 21);
  gate_sc<1, 3>(v, gates + 16 * 22);
  gate_sc<5, 2>(v, gates + 16 * 32);
  gate_sc<3, 4>(v, gates + 16 * 33);
  gate_sc<0, 1>(v, gates + 16 * 34);
  gate_sc<4, 5>(v, gates + 16 * 44);
  gate_sc<1, 3>(v, gates + 16 * 45);
  TRANS(JA1, JW1, 5, 2);
  // Phase W (r=[j6,j7,j5,j8,j9,j10])
  gate_sc<4, 5>(v, gates + 16 * 41);
  gate_sc<1, 3>(v, gates + 16 * 42);
  gate_sc<2, 0>(v, gates + 16 * 43);

  const long long ob = ((long long)b) << 14;
#pragma unroll
  for (int r = 0; r < 64; ++r) out[ob | JW1(t, r)] = v[r];
}

// ---------------- Pass 2a: 8 gates, tile = {0..6} u {11..17}, 256 thr --------
// local j0..6 = global 0..6; j7..13 = global 11..17. block bits {7..10}u{18..23}
// F3 layout: r=[j0,j1,j10,j11,j12,j13], t=j2..j9
#define JF3(t, r) (((r) & 3) | (((t) & 255) << 2) | (((r) >> 2) << 10))
// W2a layout: r=[j0,j7,j10,j8,j9,j11], t0..5=j1..j6, t6=j12, t7=j13
#define JW2A(t, r) (((r) & 1) | (((t) & 63) << 1) | ((((r) >> 1) & 1) << 7) | ((((r) >> 3) & 1) << 8) | ((((r) >> 4) & 1) << 9) | ((((r) >> 2) & 1) << 10) | ((((r) >> 5) & 1) << 11) | ((((t) >> 6) & 1) << 12) | ((((t) >> 7) & 1) << 13))
// buf index: delete split bits j10, j0; swizzle
#define BIDX_A(j) BSWZ(DEL(DEL((j), 10), 0))

__global__ __launch_bounds__(256) void k_pass2a(
    const float* __restrict__ gates, float* __restrict__ out) {
  __shared__ float buf[4096];
  const int t = threadIdx.x;
  const int b = blockIdx.x;
  const long long base0 = ((long long)(b & 15) << 7) | ((long long)(b >> 4) << 18);

  float v[64];
  // load in F3 layout: float4, 2x512B runs per wave-inst
#pragma unroll
  for (int c = 0; c < 16; ++c) {
    const int jb = (c << 10) | (t << 2);
    float4 x = *(const float4*)(&out[base0 + (jb & 127) + ((long long)(jb >> 7) << 11)]);
    v[4 * c] = x.x; v[4 * c + 1] = x.y; v[4 * c + 2] = x.z; v[4 * c + 3] = x.w;
  }
  // Phase F3 (r2..r5 = j10..j13): g3(j12,j13) g4(j10,j11) g15(j11,j12)
  gate_sc<4, 5>(v, gates + 16 * 3);
  gate_sc<2, 3>(v, gates + 16 * 4);
  gate_sc<3, 4>(v, gates + 16 * 15);
  TRANS4(JF3, JW2A, 2, 0, BIDX_A);  // split j10@r2, j0@r0 (both layouts)
  // Phase W2a (r=[j0,j7,j10,j8,j9,j11]): g16(j9,j10) g27(j10,j11) g28(j8,j9)
  //                                       g39(j9,j10) g40(j7,j8)
  gate_sc<4, 2>(v, gates + 16 * 16);
  gate_sc<2, 5>(v, gates + 16 * 27);
  gate_sc<3, 4>(v, gates + 16 * 28);
  gate_sc<4, 2>(v, gates + 16 * 39);
  gate_sc<1, 3>(v, gates + 16 * 40);

  // store float2: one contiguous 512B run per wave-inst
#pragma unroll
  for (int h = 0; h < 32; ++h) {
    const int j = JW2A(t, 2 * h);  // even j (j0 = 0)
    float2 w2; w2.x = v[2 * h]; w2.y = v[2 * h + 1];
    *(float2*)(&out[base0 + (j & 127) + ((long long)(j >> 7) << 11)]) = w2;
  }
}

// ---------------- Pass 2b: 14 gates, tile = {0..4} u {15..23}, 256 thr -------
// local j0..4 = global 0..4; j5..13 = global 15..23. block = global 5..14
// F layout: r=[j0,j1,j10,j11,j12,j13], t=j2..j9  (JF3 reused)
// W1b layout: r=[j0,j8,j9,j10,j12,j11], t0..6=j1..j7, t7=j13
#define JW1B(t, r) (((r) & 1) | (((t) & 127) << 1) | ((((r) >> 1) & 1) << 8) | ((((r) >> 2) & 1) << 9) | ((((r) >> 3) & 1) << 10) | ((((r) >> 5) & 1) << 11) | ((((r) >> 4) & 1) << 12) | ((((t) >> 7) & 1) << 13))
// W2b layout: r=[j5,j8,j9,j7,j6,j10], t0..4=j0..j4, t5=j11, t6=j12, t7=j13
#define JW2B(t, r) (((t) & 31) | (((r) & 1) << 5) | ((((r) >> 4) & 1) << 6) | ((((r) >> 3) & 1) << 7) | ((((r) >> 1) & 1) << 8) | ((((r) >> 2) & 1) << 9) | ((((r) >> 5) & 1) << 10) | ((((t) >> 5) & 1) << 11) | ((((t) >> 6) & 1) << 12) | ((((t) >> 7) & 1) << 13))
// buf indices
#define BIDX_B1(j) BSWZ(DEL(DEL((j), 12), 0))   // split j12@r4, j0@r0
#define BIDX_B2(j) BSWZ(DEL(DEL((j), 9), 8))    // split j9@r2, j8@r1

__global__ __launch_bounds__(256) void k_pass2b(
    const float* __restrict__ gates, float* __restrict__ out) {
  __shared__ float buf[4096];
  const int t = threadIdx.x;
  const int b = blockIdx.x;  // global bits 5..14
  const long long bb = (long long)b << 5;

  float v[64];
  // load in F layout: float4, 8x128B runs per wave-inst
#pragma unroll
  for (int c = 0; c < 16; ++c) {
    const int jb = (c << 10) | (t << 2);
    float4 x = *(const float4*)(&out[(jb & 31) + bb + ((long long)(jb >> 5) << 15)]);
    v[4 * c] = x.x; v[4 * c + 1] = x.y; v[4 * c + 2] = x.z; v[4 * c + 3] = x.w;
  }
  // Phase F (r2..r5 = j10..13): g0(j12,j13) g1(j10,j11) g12(j11,j12) g23(j12,j13)
  gate_sc<4, 5>(v, gates + 16 * 0);
  gate_sc<2, 3>(v, gates + 16 * 1);
  gate_sc<3, 4>(v, gates + 16 * 12);
  gate_sc<4, 5>(v, gates + 16 * 23);
  TRANS4(JF3, JW1B, 4, 0, BIDX_B1);  // split j12@r4, j0@r0
  // Phase W1b (r=[j0,j8,j9,j10,j12,j11]): g2(j8,j9) g13(j9,j10) g24(j10,j11)
  //                                        g35(j11,j12)
  gate_sc<1, 2>(v, gates + 16 * 2);
  gate_sc<2, 3>(v, gates + 16 * 13);
  gate_sc<3, 5>(v, gates + 16 * 24);
  gate_sc<5, 4>(v, gates + 16 * 35);
  TRANS4(JW1B, JW2B, 2, 1, BIDX_B2);  // split j9@r2, j8@r1
  // Phase W2b (r=[j5,j8,j9,j7,j6,j10]): g14(j7,j8) g25(j8,j9) g26(j6,j7)
  //                                      g36(j9,j10) g37(j7,j8) g38(j5,j6)
  gate_sc<3, 1>(v, gates + 16 * 14);
  gate_sc<1, 2>(v, gates + 16 * 25);
  gate_sc<4, 3>(v, gates + 16 * 26);
  gate_sc<2, 5>(v, gates + 16 * 36);
  gate_sc<3, 1>(v, gates + 16 * 37);
  gate_sc<0, 4>(v, gates + 16 * 38);

  // store scalar: 2x128B runs per wave-inst
#pragma unroll
  for (int r = 0; r < 64; ++r) {
    const int j = JW2B(t, r);
    out[(j & 31) + bb + ((long long)(j >> 5) << 15)] = v[r];
  }
}

extern "C" void kernel_launch(void* const* d_in, const int* in_sizes, int n_in,
                              void* d_out, int out_size, void* d_ws, size_t ws_size,
                              hipStream_t stream) {
  const float* states = (const float*)d_in[0];  // (24, 2) f32
  const float* gates = (const float*)d_in[1];   // (46, 2,2,2,2) f32
  float* out = (float*)d_out;                   // 2^24 f32

  k_pass1<<<1024, 256, 0, stream>>>(states, gates, out);
  k_pass2a<<<1024, 256, 0, stream>>>(gates, out);
  k_pass2b<<<1024, 256, 0, stream>>>(gates, out);
}

// Round 8
// 182.529 us; speedup vs baseline: 1.0852x; 1.0067x over previous
//
#include <hip/hip_runtime.h>

// 24-qubit brickwork circuit. 3 passes, register-resident gates.
// State: flat index i in [0, 2^24), wire w <-> bit (23-w).
// Gate on wires (w,w+1): p1 = 22-w (low bit), p0 = p1+1. M[v][u] = G[u0,v0,u1,v1].
//
// All layout maps are GF(2)-linear with disjoint t/r fields:
//   F(J(t,r)) = F(J(t,0)) ^ F(J(0,r)),  F(J(0,r)) = compile-time const.
// So transposes use buf[A_t ^ C_r] (1 VALU/access) and global I/O uses
// base-pointer + constant offsets. Addresses are BIT-IDENTICAL to round 7
// (same swizzles, same verified <=2 lanes/bank patterns, 0 conflicts).

#define SWZ(j) ((j) ^ (((j) >> 6) & 15) ^ ((((j) >> 10) & 1) << 4))
#define DEL(x, S) (((x) & ((1 << (S)) - 1)) | (((x) >> ((S) + 1)) << (S)))
#define BSWZ(x) ((x) ^ (((x) >> 5) & 31))

// Gate acting on reg bits B0 (holds p1 / u1) and B1 (holds p0 / u0).
template<int B0, int B1>
__device__ __forceinline__ void gate_sc(float v[64], const float* __restrict__ g) {
  float m[16];
#pragma unroll
  for (int vv = 0; vv < 4; ++vv)
#pragma unroll
    for (int uu = 0; uu < 4; ++uu)
      m[vv * 4 + uu] = g[(uu >> 1) * 8 + (vv >> 1) * 4 + (uu & 1) * 2 + (vv & 1)];
  constexpr int S1 = 1 << B0;  // u1 stride
  constexpr int S0 = 1 << B1;  // u0 stride
#pragma unroll
  for (int b = 0; b < 64; ++b) {
    if (b & (S0 | S1)) continue;
    const float a0 = v[b], a1 = v[b + S1], a2 = v[b + S0], a3 = v[b + S0 + S1];
    v[b]           = m[0]  * a0 + m[1]  * a1 + m[2]  * a2 + m[3]  * a3;
    v[b + S1]      = m[4]  * a0 + m[5]  * a1 + m[6]  * a2 + m[7]  * a3;
    v[b + S0]      = m[8]  * a0 + m[9]  * a1 + m[10] * a2 + m[11] * a3;
    v[b + S0 + S1] = m[12] * a0 + m[13] * a1 + m[14] * a2 + m[15] * a3;
  }
}

// ---------- pass1 layouts (14-bit j, t = 8 bits) ----------
#define JB1(t, r) ((t) | ((r) << 8))
#define JM1(t, r) (((t) & 15) | ((((r) >> 1) & 15) << 4) | (((r) & 1) << 8) | (((r) >> 5) << 9) | (((t) >> 4) << 10))
#define JA1(t, r) (((r) & 3) | ((((r) >> 3) & 7) << 2) | ((((r) >> 2) & 1) << 5) | ((t) << 6))
#define JW1(t, r) (((t) & 31) | ((((r) >> 2) & 1) << 5) | (((r) & 1) << 6) | ((((r) >> 1) & 1) << 7) | ((((r) >> 3) & 7) << 8) | (((t) >> 5) << 11))

// 2-stage in-place transpose (pass1, buf 8192 floats), XOR-decomposed addrs.
#define TRANS(JW, JR, S, RBIT)                                        \
  do {                                                                \
    const int AW = DEL(SWZ(JW(t, 0)), S);                             \
    const int AR = DEL(SWZ(JR(t, 0)), S);                             \
    _Pragma("unroll")                                                 \
    for (int r = 0; r < 64; ++r) if (((r >> (RBIT)) & 1) == 0)        \
      buf[AW ^ DEL(SWZ(JW(0, r)), S)] = v[r];                         \
    __syncthreads();                                                  \
    _Pragma("unroll")                                                 \
    for (int r = 0; r < 64; ++r) if (((r >> (RBIT)) & 1) == 0)        \
      v[r] = buf[AR ^ DEL(SWZ(JR(0, r)), S)];                         \
    __syncthreads();                                                  \
    _Pragma("unroll")                                                 \
    for (int r = 0; r < 64; ++r) if (((r >> (RBIT)) & 1) == 1)        \
      buf[AW ^ DEL(SWZ(JW(0, r)), S)] = v[r];                         \
    __syncthreads();                                                  \
    _Pragma("unroll")                                                 \
    for (int r = 0; r < 64; ++r) if (((r >> (RBIT)) & 1) == 1)        \
      v[r] = buf[AR ^ DEL(SWZ(JR(0, r)), S)];                         \
    __syncthreads();                                                  \
  } while (0)

// 4-stage in-place transpose (pass2, buf 4096 floats), XOR-decomposed addrs.
#define T4STAGE(JW, JR, RA, RB, SA, SB, BIDX, AW, AR)                 \
    _Pragma("unroll")                                                 \
    for (int r = 0; r < 64; ++r)                                      \
      if ((((r >> (RA)) & 1) == (SA)) && (((r >> (RB)) & 1) == (SB))) \
        buf[(AW) ^ BIDX(JW(0, r))] = v[r];                            \
    __syncthreads();                                                  \
    _Pragma("unroll")                                                 \
    for (int r = 0; r < 64; ++r)                                      \
      if ((((r >> (RA)) & 1) == (SA)) && (((r >> (RB)) & 1) == (SB))) \
        v[r] = buf[(AR) ^ BIDX(JR(0, r))];                            \
    __syncthreads();

#define TRANS4(JW, JR, RA, RB, BIDX)                                  \
  do {                                                                \
    const int AW4 = BIDX(JW(t, 0));                                   \
    const int AR4 = BIDX(JR(t, 0));                                   \
    T4STAGE(JW, JR, RA, RB, 0, 0, BIDX, AW4, AR4)                     \
    T4STAGE(JW, JR, RA, RB, 0, 1, BIDX, AW4, AR4)                     \
    T4STAGE(JW, JR, RA, RB, 1, 0, BIDX, AW4, AR4)                     \
    T4STAGE(JW, JR, RA, RB, 1, 1, BIDX, AW4, AR4)                     \
  } while (0)

// ---------------- Pass 1: init + 24 gates on bits 0..13 (wires 10..23) -------
__global__ __launch_bounds__(256) void k_pass1(
    const float* __restrict__ states, const float* __restrict__ gates,
    float* __restrict__ out) {
  __shared__ float buf[8192];
  const int t = threadIdx.x;
  const int b = blockIdx.x;  // global bits 14..23 (wires 9..0)

  {
    float p = 1.f;
    for (int k = 0; k < 8; ++k) p *= states[(23 - k) * 2 + ((t >> k) & 1)];
    buf[t] = p;  // sLo over j0..7 (wires 23..16)
    if (t < 64) {
      float q = 1.f;
      for (int k = 0; k < 6; ++k) q *= states[(15 - k) * 2 + ((t >> k) & 1)];
      buf[256 + t] = q;  // sHi over j8..13 (wires 15..10)
    }
  }
  float pref = 1.f;
  for (int k = 0; k < 10; ++k) pref *= states[(9 - k) * 2 + ((b >> k) & 1)];
  __syncthreads();

  float v[64];
  const float plT = pref * buf[t];
#pragma unroll
  for (int r = 0; r < 64; ++r) v[r] = plT * buf[256 + r];  // B layout: r=j8..13
  __syncthreads();

  // Phase B (r=[j8..13])
  gate_sc<4, 5>(v, gates + 16 * 5);
  gate_sc<2, 3>(v, gates + 16 * 6);
  gate_sc<0, 1>(v, gates + 16 * 7);
  gate_sc<3, 4>(v, gates + 16 * 17);
  gate_sc<1, 2>(v, gates + 16 * 18);
  gate_sc<2, 3>(v, gates + 16 * 29);
  TRANS(JB1, JM1, 8, 0);
  // Phase M (r=[j8,j4,j5,j6,j7,j9])
  gate_sc<3, 4>(v, gates + 16 * 8);
  gate_sc<1, 2>(v, gates + 16 * 9);
  gate_sc<4, 0>(v, gates + 16 * 19);
  gate_sc<2, 3>(v, gates + 16 * 20);
  gate_sc<0, 5>(v, gates + 16 * 30);
  gate_sc<3, 4>(v, gates + 16 * 31);
  TRANS(JM1, JA1, 5, 2);
  // Phase A (r=[j0,j1,j5,j2,j3,j4])
  gate_sc<3, 4>(v, gates + 16 * 10);
  gate_sc<0, 1>(v, gates + 16 * 11);
  gate_sc<4, 5>(v, gates + 16 * 21);
  gate_sc<1, 3>(v, gates + 16 * 22);
  gate_sc<5, 2>(v, gates + 16 * 32);
  gate_sc<3, 4>(v, gates + 16 * 33);
  gate_sc<0, 1>(v, gates + 16 * 34);
  gate_sc<4, 5>(v, gates + 16 * 44);
  gate_sc<1, 3>(v, gates + 16 * 45);
  TRANS(JA1, JW1, 5, 2);
  // Phase W (r=[j6,j7,j5,j8,j9,j10])
  gate_sc<4, 5>(v, gates + 16 * 41);
  gate_sc<1, 3>(v, gates + 16 * 42);
  gate_sc<2, 0>(v, gates + 16 * 43);

  // store: base-ptr + const offsets (JW1(t,r) = JW1(t,0) | JW1(0,r), disjoint)
  float* po = out + (((long long)b) << 14) + (t & 31) + ((long long)(t >> 5) << 11);
#pragma unroll
  for (int r = 0; r < 64; ++r) po[JW1(0, r)] = v[r];  // 2x128B runs/inst
}

// ---------------- Pass 2a: 8 gates, tile = {0..6} u {11..17}, 256 thr --------
// local j0..6 = global 0..6; j7..13 = global 11..17. block bits {7..10}u{18..23}
#define JF3(t, r) (((r) & 3) | (((t) & 255) << 2) | (((r) >> 2) << 10))
#define JW2A(t, r) (((r) & 1) | (((t) & 63) << 1) | ((((r) >> 1) & 1) << 7) | ((((r) >> 3) & 1) << 8) | ((((r) >> 4) & 1) << 9) | ((((r) >> 2) & 1) << 10) | ((((r) >> 5) & 1) << 11) | ((((t) >> 6) & 1) << 12) | ((((t) >> 7) & 1) << 13))
#define BIDX_A(j) BSWZ(DEL(DEL((j), 10), 0))

__global__ __launch_bounds__(256) void k_pass2a(
    const float* __restrict__ gates, float* __restrict__ out) {
  __shared__ float buf[4096];
  const int t = threadIdx.x;
  const int b = blockIdx.x;
  const long long base0 = ((long long)(b & 15) << 7) | ((long long)(b >> 4) << 18);

  float v[64];
  // load in F3 layout: float4, 2x512B runs per wave-inst
  const float* pi = out + base0 + ((t & 31) << 2) + ((long long)(t >> 5) << 11);
#pragma unroll
  for (int c = 0; c < 16; ++c) {
    float4 x = *(const float4*)(pi + ((long long)c << 14));
    v[4 * c] = x.x; v[4 * c + 1] = x.y; v[4 * c + 2] = x.z; v[4 * c + 3] = x.w;
  }
  // Phase F3 (r2..r5 = j10..j13): g3(j12,j13) g4(j10,j11) g15(j11,j12)
  gate_sc<4, 5>(v, gates + 16 * 3);
  gate_sc<2, 3>(v, gates + 16 * 4);
  gate_sc<3, 4>(v, gates + 16 * 15);
  TRANS4(JF3, JW2A, 2, 0, BIDX_A);  // split j10@r2, j0@r0 (both layouts)
  // Phase W2a (r=[j0,j7,j10,j8,j9,j11]): g16(j9,j10) g27(j10,j11) g28(j8,j9)
  //                                       g39(j9,j10) g40(j7,j8)
  gate_sc<4, 2>(v, gates + 16 * 16);
  gate_sc<2, 5>(v, gates + 16 * 27);
  gate_sc<3, 4>(v, gates + 16 * 28);
  gate_sc<4, 2>(v, gates + 16 * 39);
  gate_sc<1, 3>(v, gates + 16 * 40);

  // store float2: one contiguous 512B run per wave-inst
  float* po = out + base0 + ((t & 63) << 1) + ((long long)(t >> 6) << 16);
#pragma unroll
  for (int h = 0; h < 32; ++h) {
    const int cr = (JW2A(0, 2 * h) & 127) + ((JW2A(0, 2 * h) >> 7) << 11);
    float2 w2; w2.x = v[2 * h]; w2.y = v[2 * h + 1];
    *(float2*)(po + cr) = w2;
  }
}

// ---------------- Pass 2b: 14 gates, tile = {0..4} u {15..23}, 256 thr -------
// local j0..4 = global 0..4; j5..13 = global 15..23. block = global 5..14
#define JW1B(t, r) (((r) & 1) | (((t) & 127) << 1) | ((((r) >> 1) & 1) << 8) | ((((r) >> 2) & 1) << 9) | ((((r) >> 3) & 1) << 10) | ((((r) >> 5) & 1) << 11) | ((((r) >> 4) & 1) << 12) | ((((t) >> 7) & 1) << 13))
#define JW2B(t, r) (((t) & 31) | (((r) & 1) << 5) | ((((r) >> 4) & 1) << 6) | ((((r) >> 3) & 1) << 7) | ((((r) >> 1) & 1) << 8) | ((((r) >> 2) & 1) << 9) | ((((r) >> 5) & 1) << 10) | ((((t) >> 5) & 1) << 11) | ((((t) >> 6) & 1) << 12) | ((((t) >> 7) & 1) << 13))
#define BIDX_B1(j) BSWZ(DEL(DEL((j), 12), 0))   // split j12@r4, j0@r0
#define BIDX_B2(j) BSWZ(DEL(DEL((j), 9), 8))    // split j9@r2, j8@r1

__global__ __launch_bounds__(256) void k_pass2b(
    const float* __restrict__ gates, float* __restrict__ out) {
  __shared__ float buf[4096];
  const int t = threadIdx.x;
  const int b = blockIdx.x;  // global bits 5..14
  const long long bb = (long long)b << 5;

  float v[64];
  // load in F layout: float4, 8x128B runs per wave-inst
  const float* pi = out + ((t & 7) << 2) + bb + ((long long)(t >> 3) << 15);
#pragma unroll
  for (int c = 0; c < 16; ++c) {
    float4 x = *(const float4*)(pi + ((long long)c << 20));
    v[4 * c] = x.x; v[4 * c + 1] = x.y; v[4 * c + 2] = x.z; v[4 * c + 3] = x.w;
  }
  // Phase F (r2..r5 = j10..13): g0(j12,j13) g1(j10,j11) g12(j11,j12) g23(j12,j13)
  gate_sc<4, 5>(v, gates + 16 * 0);
  gate_sc<2, 3>(v, gates + 16 * 1);
  gate_sc<3, 4>(v, gates + 16 * 12);
  gate_sc<4, 5>(v, gates + 16 * 23);
  TRANS4(JF3, JW1B, 4, 0, BIDX_B1);  // split j12@r4, j0@r0
  // Phase W1b (r=[j0,j8,j9,j10,j12,j11]): g2(j8,j9) g13(j9,j10) g24(j10,j11)
  //                                        g35(j11,j12)
  gate_sc<1, 2>(v, gates + 16 * 2);
  gate_sc<2, 3>(v, gates + 16 * 13);
  gate_sc<3, 5>(v, gates + 16 * 24);
  gate_sc<5, 4>(v, gates + 16 * 35);
  TRANS4(JW1B, JW2B, 2, 1, BIDX_B2);  // split j9@r2, j8@r1
  // Phase W2b (r=[j5,j8,j9,j7,j6,j10]): g14(j7,j8) g25(j8,j9) g26(j6,j7)
  //                                      g36(j9,j10) g37(j7,j8) g38(j5,j6)
  gate_sc<3, 1>(v, gates + 16 * 14);
  gate_sc<1, 2>(v, gates + 16 * 25);
  gate_sc<4, 3>(v, gates + 16 * 26);
  gate_sc<2, 5>(v, gates + 16 * 36);
  gate_sc<3, 1>(v, gates + 16 * 37);
  gate_sc<0, 4>(v, gates + 16 * 38);

  // store scalar: 2x128B runs per wave-inst, base-ptr + const offsets
  float* po = out + (t & 31) + bb + ((long long)(t >> 5) << 21);
#pragma unroll
  for (int r = 0; r < 64; ++r) po[(JW2B(0, r) >> 5) << 15] = v[r];
}

extern "C" void kernel_launch(void* const* d_in, const int* in_sizes, int n_in,
                              void* d_out, int out_size, void* d_ws, size_t ws_size,
                              hipStream_t stream) {
  const float* states = (const float*)d_in[0];  // (24, 2) f32
  const float* gates = (const float*)d_in[1];   // (46, 2,2,2,2) f32
  float* out = (float*)d_out;                   // 2^24 f32

  k_pass1<<<1024, 256, 0, stream>>>(states, gates, out);
  k_pass2a<<<1024, 256, 0, stream>>>(gates, out);
  k_pass2b<<<1024, 256, 0, stream>>>(gates, out);
}